// Round 4
// baseline (725.695 us; speedup 1.0000x reference)
//
#include <hip/hip_runtime.h>
#include <hip/hip_bf16.h>
#include <hip/hip_cooperative_groups.h>

namespace cg = cooperative_groups;

#define HIDDEN 128
#define DEPTH 4
#define INTER 512
#define NSTATE 16
#define DT_RANK 8
#define EPS_RMS 1e-5f
#define MTOK 512            // B*T
#define KIN 150528

typedef __attribute__((ext_vector_type(8))) short bf16x8;
typedef __attribute__((ext_vector_type(4))) float f32x4;

__device__ __forceinline__ unsigned short f2bf(float f) {
  unsigned int u = __builtin_bit_cast(unsigned int, f);
  u += 0x7fffu + ((u >> 16) & 1u);
  return (unsigned short)(u >> 16);
}
__device__ __forceinline__ float silu_f(float x) {
  return x / (1.0f + __expf(-x));
}

// ---------------------------------------------------------------------------
// zero_part: 4 MB partial buffer zero (1024 x 256 x float4).
// ---------------------------------------------------------------------------
__global__ __launch_bounds__(256) void zero_part(float* __restrict__ p)
{
  const size_t i = (size_t)blockIdx.x * 256 + threadIdx.x;
  ((float4*)p)[i] = (float4){0.f, 0.f, 0.f, 0.f};
}

// ---------------------------------------------------------------------------
// Projection GEMM v3 (unchanged from R3, ~137 us): zero-duplication tiling.
// grid 256 = mb(4) x kb(64); NT=128 (x read once), k-chunk 128 -> 512-B
// bursts; 64 KB LDS bf16, swizzled; atomicAdd into 16 slices.
// ---------------------------------------------------------------------------
__global__ __launch_bounds__(512) void proj_gemm(
    const float* __restrict__ x, const float* __restrict__ w,
    float* __restrict__ partial)
{
  const int bid = blockIdx.x;          // 0..255
  const int mb = (bid >> 3) & 3;       // 0..3  (M-tile of 128 rows)
  const int kb = (bid & 7) + (bid >> 5) * 8;   // 0..63 (XCD-clustered)
  const int nchunk = 18 + (kb < 24 ? 1 : 0);
  const int c0 = kb * 18 + (kb < 24 ? kb : 24);

  __shared__ char sm[256 * 256];       // 256 rows (x:0-127, w:128-255) x 256 B

  const int tid = threadIdx.x;
  const int lane = tid & 63;
  const int wv = tid >> 6;             // 0..7
  const int wm2 = wv >> 2;             // 0..1  M-half (64 rows)
  const int wn4 = wv & 3;              // 0..3  N-quarter (32 cols)
  const int fr = lane & 15;
  const int kq = lane >> 4;            // 0..3
  const int l31 = lane & 31;
  const int rpar = lane >> 5;          // 0/1

  const float* gptr = (wv < 4)
      ? (x + (size_t)(mb * 128 + wv * 32 + rpar) * KIN + l31 * 4)
      : (w + (size_t)((wv - 4) * 32 + rpar) * KIN + l31 * 4);

  f32x4 acc[4][2];
  #pragma unroll
  for (int mi = 0; mi < 4; ++mi) {
    acc[mi][0] = (f32x4){0.f, 0.f, 0.f, 0.f};
    acc[mi][1] = (f32x4){0.f, 0.f, 0.f, 0.f};
  }

  float4 rv[16];
  {
    const float* base = gptr + (size_t)c0 * 128;
    #pragma unroll
    for (int j = 0; j < 16; ++j)
      rv[j] = *(const float4*)(base + (size_t)(j * 2) * KIN);
  }

  for (int cc = 0; cc < nchunk; ++cc) {
    #pragma unroll
    for (int j = 0; j < 16; ++j) {
      const int r = wv * 32 + j * 2 + rpar;
      const int phys = (l31 * 8) ^ ((r & 7) << 4);
      ushort4 bq = {f2bf(rv[j].x), f2bf(rv[j].y), f2bf(rv[j].z), f2bf(rv[j].w)};
      *(ushort4*)(sm + r * 256 + phys) = bq;
    }
    __syncthreads();
    if (cc + 1 < nchunk) {
      const float* base = gptr + (size_t)(c0 + cc + 1) * 128;
      #pragma unroll
      for (int j = 0; j < 16; ++j)
        rv[j] = *(const float4*)(base + (size_t)(j * 2) * KIN);
    }
    #pragma unroll
    for (int ks = 0; ks < 4; ++ks) {
      const int log = ks * 64 + kq * 16;
      bf16x8 a[4];
      #pragma unroll
      for (int mi = 0; mi < 4; ++mi) {
        const int row = wm2 * 64 + mi * 16 + fr;
        a[mi] = *(const bf16x8*)(sm + row * 256 + (log ^ ((row & 7) << 4)));
      }
      #pragma unroll
      for (int ni = 0; ni < 2; ++ni) {
        const int row = 128 + wn4 * 32 + ni * 16 + fr;
        const bf16x8 b = *(const bf16x8*)(sm + row * 256 + (log ^ ((row & 7) << 4)));
        #pragma unroll
        for (int mi = 0; mi < 4; ++mi)
          acc[mi][ni] = __builtin_amdgcn_mfma_f32_16x16x32_bf16(a[mi], b, acc[mi][ni], 0, 0, 0);
      }
    }
    __syncthreads();
  }
  float* hp = partial + (size_t)(kb & 15) * (MTOK * HIDDEN);
  #pragma unroll
  for (int mi = 0; mi < 4; ++mi)
    #pragma unroll
    for (int ni = 0; ni < 2; ++ni)
      #pragma unroll
      for (int r = 0; r < 4; ++r) {
        const int row = mb * 128 + wm2 * 64 + mi * 16 + kq * 4 + r;
        const int col = wn4 * 32 + ni * 16 + fr;
        atomicAdd(hp + (size_t)row * HIDDEN + col, acc[mi][ni][r]);
      }
}

// ---------------------------------------------------------------------------
// tail_coop: the ENTIRE post-GEMM pipeline in one cooperative kernel.
// Replaces 13 dependent launches (fusedA x5, convxp x4, scan_k x4) that were
// ~20 us each (launch/drain bound; actual data per kernel <= 2 MB).
// grid 256 x 512, co-resident; 12 grid.sync()s between phases.
// ---------------------------------------------------------------------------
struct TailArgs {
  const float* part; const float* pb;
  float* h; float* hs; float* gate;
  float* uT; float* dtT; float* Bm; float* Cm; float* y;
  float* out;
  const float* ipw; const float* cw; const float* cb;
  const float* xpw; const float* dtw; const float* dtb;
  const float* Alog; const float* Dssm; const float* opw;
  const float* nw; const float* nwf;
};

__global__ __launch_bounds__(512) void tail_coop(TailArgs A)
{
  cg::grid_group grid = cg::this_grid();
  const int blk = blockIdx.x;
  const int tid = threadIdx.x;
  const int m0 = blk * 2;

  __shared__ __align__(16) char smraw[15360];

  // ---------------- phase A0: h = pb + sum(part) ; rms ; in_proj l=0 -------
  {
    float* hrow = (float*)smraw;             // [2][128]
    float* hn   = hrow + 256;                // [2][128]
    const int o2 = tid >> 1, half = tid & 1;
    const int t = o2 >> 7, d = o2 & 127;
    if (half == 0) {
      float hv = A.pb[d];
      #pragma unroll
      for (int s = 0; s < 16; ++s)
        hv += A.part[(size_t)s * (MTOK * HIDDEN) + (size_t)(m0 + t) * 128 + d];
      A.h[(size_t)(m0 + t) * 128 + d] = hv;
      hrow[t * 128 + d] = hv;
    }
    __syncthreads();
    {
      const int wvi = tid >> 6, ln = tid & 63;
      const int tt = wvi & 1;
      const float v0 = hrow[tt * 128 + ln], v1 = hrow[tt * 128 + ln + 64];
      float ss = v0 * v0 + v1 * v1;
      #pragma unroll
      for (int off = 1; off < 64; off <<= 1) ss += __shfl_xor(ss, off);
      const float rr = rsqrtf(ss * (1.0f / 128.0f) + EPS_RMS);
      if (wvi < 2) {
        hn[tt * 128 + ln]      = v0 * rr * A.nw[ln];
        hn[tt * 128 + ln + 64] = v1 * rr * A.nw[ln + 64];
      }
    }
    __syncthreads();
    #pragma unroll
    for (int j = 0; j < 4; ++j) {
      const int o = tid + j * 512;
      const int tt = o >> 10, e = o & 1023;
      const float4* hp4 = (const float4*)(hn + tt * 128);
      const float4* wp4 = (const float4*)(A.ipw + (size_t)e * 128);
      float a0 = 0.f, a1 = 0.f, a2 = 0.f, a3 = 0.f;
      #pragma unroll
      for (int kk = 0; kk < 32; ++kk) {
        const float4 hvv = hp4[kk], wv4 = wp4[kk];
        a0 += hvv.x * wv4.x; a1 += hvv.y * wv4.y;
        a2 += hvv.z * wv4.z; a3 += hvv.w * wv4.w;
      }
      const float a = (a0 + a1) + (a2 + a3);
      if (e < 512) A.hs[(size_t)(m0 + tt) * 512 + e] = a;
      else         A.gate[(size_t)(m0 + tt) * 512 + (e - 512)] = a;
    }
  }
  grid.sync();

  for (int l = 0; l < DEPTH; ++l) {
    // -------------- phase CONV(l): conv+silu -> uT ; x_proj ; dt ----------
    {
      float* hs5 = (float*)smraw;            // [5][512]
      float* u4  = hs5 + 2560;               // [2][512]
      float* si  = u4 + 1024;                // [2][40]
      const float* cw  = A.cw  + (size_t)l * 2048;
      const float* cb  = A.cb  + (size_t)l * 512;
      const float* xpw = A.xpw + (size_t)l * 40 * 512;
      const float* dtw = A.dtw + (size_t)l * 512 * 8;
      const float* dtb = A.dtb + (size_t)l * 512;
      const int b = m0 >> 8, tb0 = m0 & 255;
      for (int o = tid; o < 2560; o += 512) {
        const int j = o >> 9, i = o & 511;
        const int ct = tb0 - 3 + j;
        hs5[j * 512 + i] = (ct >= 0) ? A.hs[((size_t)b * 256 + ct) * 512 + i] : 0.f;
      }
      __syncthreads();
      #pragma unroll
      for (int j = 0; j < 2; ++j) {
        const int o = tid + j * 512;
        const int t = o >> 9, i = o & 511;
        const float4 c4v = *(const float4*)(cw + (size_t)i * 4);
        const float s = cb[i] + c4v.x * hs5[t * 512 + i] + c4v.y * hs5[(t + 1) * 512 + i]
                              + c4v.z * hs5[(t + 2) * 512 + i] + c4v.w * hs5[(t + 3) * 512 + i];
        const float uu = silu_f(s);
        u4[t * 512 + i] = uu;
        A.uT[((size_t)b * 512 + i) * 256 + tb0 + t] = uu;
      }
      __syncthreads();
      if (tid < 160) {
        const int pid = tid >> 1, half = tid & 1;
        const int t = pid / 40, e = pid % 40;
        const float4* up = (const float4*)(u4 + t * 512 + half * 256);
        const float4* wp = (const float4*)(xpw + (size_t)e * 512 + half * 256);
        float a0 = 0.f, a1 = 0.f, a2 = 0.f, a3 = 0.f;
        #pragma unroll 8
        for (int kk = 0; kk < 64; ++kk) {
          const float4 uv = up[kk], wv4 = wp[kk];
          a0 += uv.x * wv4.x; a1 += uv.y * wv4.y;
          a2 += uv.z * wv4.z; a3 += uv.w * wv4.w;
        }
        float a = (a0 + a1) + (a2 + a3);
        a += __shfl_xor(a, 1);
        if (half == 0) si[t * 40 + e] = a;
      }
      __syncthreads();
      if (tid < 64) {
        const int t = tid >> 5, q = tid & 31;
        if (q < 16) A.Bm[(size_t)(m0 + t) * 16 + q] = si[t * 40 + 8 + q];
        else        A.Cm[(size_t)(m0 + t) * 16 + (q - 16)] = si[t * 40 + 24 + (q - 16)];
      }
      #pragma unroll
      for (int j = 0; j < 2; ++j) {
        const int o = tid + j * 512;
        const int i = o >> 1, t = o & 1;
        float a0 = dtb[i];
        const float* dr = dtw + (size_t)i * 8;
        #pragma unroll
        for (int r = 0; r < 8; ++r) a0 += si[t * 40 + r] * dr[r];
        const float sp = (a0 > 20.f) ? a0 : log1pf(__expf(a0));
        A.dtT[((size_t)b * 512 + i) * 256 + tb0 + t] = sp;
      }
    }
    grid.sync();

    // -------------- phase SCAN(l): 4 scans/block (2 parallel x 2 rounds) --
    {
      float* dt_l = (float*)smraw;           // [2][256]
      float* u_l  = dt_l + 512;              // [2][256]
      float* e_l  = u_l + 512;               // [2][16*17]
      float* P_l  = e_l + 544;               // [2][16*17]
      const float* Alg = A.Alog + (size_t)l * INTER * NSTATE;
      const float* Dsp = A.Dssm + (size_t)l * INTER;
      const int sub = tid >> 8;              // 0/1
      const int t2 = tid & 255;
      const int c = t2 >> 4, n = t2 & 15;
      for (int rd = 0; rd < 2; ++rd) {
        const int unit = blk * 4 + sub * 2 + rd;
        const int b = unit >> 9, i = unit & 511;
        dt_l[sub * 256 + t2] = A.dtT[((size_t)b * 512 + i) * 256 + t2];
        u_l [sub * 256 + t2] = A.uT [((size_t)b * 512 + i) * 256 + t2];
        const float Av = -__expf(Alg[(size_t)i * 16 + n]);
        const float Dv = Dsp[i];
        float Bv[16], Cv[16];
        #pragma unroll
        for (int j = 0; j < 16; ++j) {
          const int t = c * 16 + j;
          Bv[j] = A.Bm[(size_t)b * 4096 + t * 16 + n];
          Cv[j] = A.Cm[(size_t)b * 4096 + t * 16 + n];
        }
        __syncthreads();
        float aj[16];
        float s = 0.f, P = 1.f;
        #pragma unroll
        for (int j = 0; j < 16; ++j) {     // pass 1: local scan from 0
          const int t = c * 16 + j;
          const float dtv = dt_l[sub * 256 + t];
          const float a = __expf(Av * dtv);
          aj[j] = a;
          s = a * s + dtv * Bv[j] * u_l[sub * 256 + t];
          P *= a;
        }
        e_l[sub * 272 + c * 17 + n] = s;
        P_l[sub * 272 + c * 17 + n] = P;
        __syncthreads();
        float s0 = 0.f;                    // stitch chunk prefixes
        for (int cc = 0; cc < c; ++cc)
          s0 = P_l[sub * 272 + cc * 17 + n] * s0 + e_l[sub * 272 + cc * 17 + n];
        s = s0;
        #pragma unroll
        for (int j = 0; j < 16; ++j) {     // pass 2: replay with true state
          const int t = c * 16 + j;
          const float dtv = dt_l[sub * 256 + t];
          s = aj[j] * s + dtv * Bv[j] * u_l[sub * 256 + t];
          float p = s * Cv[j];
          p += __shfl_xor(p, 1); p += __shfl_xor(p, 2);
          p += __shfl_xor(p, 4); p += __shfl_xor(p, 8);
          if (n == 0)
            A.y[((size_t)b * 256 + t) * 512 + i] = p + u_l[sub * 256 + t] * Dv;
        }
        __syncthreads();
      }
    }
    grid.sync();

    // -------------- phase FA(l): out_proj+res ; rms ; in_proj(l+1)|out ----
    {
      float* y2   = (float*)smraw;           // [2][512]
      float* hrow = y2 + 1024;               // [2][128]
      float* hn   = hrow + 256;              // [2][128]
      const float* opw = A.opw + (size_t)l * 128 * 512;
      const int o2 = tid >> 1, half = tid & 1;
      const int t = o2 >> 7, d = o2 & 127;
      #pragma unroll
      for (int j = 0; j < 2; ++j) {
        const int o = tid + j * 512;
        const int tt = o >> 9, i = o & 511;
        const float yv = A.y[(size_t)(m0 + tt) * 512 + i];
        const float g  = A.gate[(size_t)(m0 + tt) * 512 + i];
        y2[tt * 512 + i] = yv * silu_f(g);
      }
      __syncthreads();
      {
        const float4* yp = (const float4*)(y2 + t * 512 + half * 256);
        const float4* wp = (const float4*)(opw + (size_t)d * 512 + half * 256);
        float a0 = 0.f, a1 = 0.f, a2 = 0.f, a3 = 0.f;
        #pragma unroll 8
        for (int kk = 0; kk < 64; ++kk) {
          const float4 yv = yp[kk], wv4 = wp[kk];
          a0 += yv.x * wv4.x; a1 += yv.y * wv4.y;
          a2 += yv.z * wv4.z; a3 += yv.w * wv4.w;
        }
        float a = (a0 + a1) + (a2 + a3);
        a += __shfl_xor(a, 1);
        const float hv = A.h[(size_t)(m0 + t) * 128 + d] + a;
        if (l < 3 && half == 0) A.h[(size_t)(m0 + t) * 128 + d] = hv;
        if (half == 0) hrow[t * 128 + d] = hv;
      }
      __syncthreads();
      const float* nwp = (l < 3) ? (A.nw + (size_t)(l + 1) * 128) : A.nwf;
      {
        const int wvi = tid >> 6, ln = tid & 63;
        const int tt = wvi & 1;
        const float v0 = hrow[tt * 128 + ln], v1 = hrow[tt * 128 + ln + 64];
        float ss = v0 * v0 + v1 * v1;
        #pragma unroll
        for (int off = 1; off < 64; off <<= 1) ss += __shfl_xor(ss, off);
        const float rr = rsqrtf(ss * (1.0f / 128.0f) + EPS_RMS);
        if (l == 3) {
          if (wvi < 2) {
            A.out[(size_t)(m0 + tt) * 128 + ln]      = v0 * rr * nwp[ln];
            A.out[(size_t)(m0 + tt) * 128 + ln + 64] = v1 * rr * nwp[ln + 64];
          }
        } else if (wvi < 2) {
          hn[tt * 128 + ln]      = v0 * rr * nwp[ln];
          hn[tt * 128 + ln + 64] = v1 * rr * nwp[ln + 64];
        }
      }
      if (l < 3) {
        __syncthreads();
        const float* ipw = A.ipw + (size_t)(l + 1) * 1024 * 128;
        #pragma unroll
        for (int j = 0; j < 4; ++j) {
          const int o = tid + j * 512;
          const int tt = o >> 10, e = o & 1023;
          const float4* hp4 = (const float4*)(hn + tt * 128);
          const float4* wp4 = (const float4*)(ipw + (size_t)e * 128);
          float a0 = 0.f, a1 = 0.f, a2 = 0.f, a3 = 0.f;
          #pragma unroll
          for (int kk = 0; kk < 32; ++kk) {
            const float4 hvv = hp4[kk], wv4 = wp4[kk];
            a0 += hvv.x * wv4.x; a1 += hvv.y * wv4.y;
            a2 += hvv.z * wv4.z; a3 += hvv.w * wv4.w;
          }
          const float a = (a0 + a1) + (a2 + a3);
          if (e < 512) A.hs[(size_t)(m0 + tt) * 512 + e] = a;
          else         A.gate[(size_t)(m0 + tt) * 512 + (e - 512)] = a;
        }
      }
    }
    if (l < 3) grid.sync();
  }
}

extern "C" void kernel_launch(void* const* d_in, const int* in_sizes, int n_in,
                              void* d_out, int out_size, void* d_ws, size_t ws_size,
                              hipStream_t stream)
{
  (void)in_sizes; (void)n_in; (void)out_size; (void)ws_size;
  const float* x    = (const float*)d_in[0];
  const float* pw   = (const float*)d_in[1];
  const float* pb   = (const float*)d_in[2];
  const float* ipw  = (const float*)d_in[3];
  const float* cw   = (const float*)d_in[4];
  const float* cb   = (const float*)d_in[5];
  const float* xpw  = (const float*)d_in[6];
  const float* dtw  = (const float*)d_in[7];
  const float* dtb  = (const float*)d_in[8];
  const float* Alog = (const float*)d_in[9];
  const float* Dssm = (const float*)d_in[10];
  const float* opw  = (const float*)d_in[11];
  const float* nw   = (const float*)d_in[12];
  const float* nwf  = (const float*)d_in[13];
  float* out = (float*)d_out;

  float* ws   = (float*)d_ws;                 // ~10 MB scratch
  float* part = ws;                           // 16 * 65536 (atomic-accumulated)
  float* h    = part + 16 * 65536;            // 65536
  float* hs   = h + 65536;                    // 262144
  float* gate = hs + 262144;                  // 262144
  float* uT   = gate + 262144;                // 262144
  float* dtT  = uT + 262144;                  // 262144
  float* Bm   = dtT + 262144;                 // 8192
  float* Cm   = Bm + 8192;                    // 8192
  float* y    = Cm + 8192;                    // 262144

  zero_part<<<dim3(1024), 256, 0, stream>>>(part);
  proj_gemm<<<dim3(256), 512, 0, stream>>>(x, pw, part);

  TailArgs ta;
  ta.part = part; ta.pb = pb;
  ta.h = h; ta.hs = hs; ta.gate = gate;
  ta.uT = uT; ta.dtT = dtT; ta.Bm = Bm; ta.Cm = Cm; ta.y = y;
  ta.out = out;
  ta.ipw = ipw; ta.cw = cw; ta.cb = cb;
  ta.xpw = xpw; ta.dtw = dtw; ta.dtb = dtb;
  ta.Alog = Alog; ta.Dssm = Dssm; ta.opw = opw;
  ta.nw = nw; ta.nwf = nwf;
  void* kargs[] = { &ta };
  hipLaunchCooperativeKernel((const void*)tail_coop, dim3(256), dim3(512),
                             kargs, 0, stream);
}

// Round 5
// 647.540 us; speedup vs baseline: 1.1207x; 1.1207x over previous
//
#include <hip/hip_runtime.h>
#include <hip/hip_bf16.h>

#define HIDDEN 128
#define DEPTH 4
#define INTER 512
#define NSTATE 16
#define DT_RANK 8
#define EPS_RMS 1e-5f
#define MTOK 512            // B*T
#define KIN 150528
#define NBLK 256            // tail persistent-kernel grid

typedef __attribute__((ext_vector_type(8))) short bf16x8;
typedef __attribute__((ext_vector_type(4))) float f32x4;

__device__ __forceinline__ unsigned short f2bf(float f) {
  unsigned int u = __builtin_bit_cast(unsigned int, f);
  u += 0x7fffu + ((u >> 16) & 1u);
  return (unsigned short)(u >> 16);
}
__device__ __forceinline__ float silu_f(float x) {
  return x / (1.0f + __expf(-x));
}

// ---------------------------------------------------------------------------
// One-shot grid barrier (slot k used exactly once per kernel execution;
// slots zeroed by zero_part each graph replay). Normal launch is safe:
// 256 blocks x 8 waves = 2048 waves <= 8192 device capacity -> all blocks
// co-resident before any can spin. cg::grid.sync() measured ~31 us/call
// (R4: 640 us kernel at 4% VALUBusy); this is the cheap replacement.
// ---------------------------------------------------------------------------
__device__ __forceinline__ void gbar(unsigned* slot)
{
  __syncthreads();
  if (threadIdx.x == 0) {
    __threadfence();   // release: prior writes visible device-wide
    (void)__hip_atomic_fetch_add(slot, 1u, __ATOMIC_ACQ_REL,
                                 __HIP_MEMORY_SCOPE_AGENT);
    while (__hip_atomic_load(slot, __ATOMIC_ACQUIRE,
                             __HIP_MEMORY_SCOPE_AGENT) < (unsigned)NBLK)
      __builtin_amdgcn_s_sleep(8);
    __threadfence();   // acquire side for this CU's caches
  }
  __syncthreads();
}

// ---------------------------------------------------------------------------
// zero_part: 4 MB partial buffer zero + barrier-slot zero.
// ---------------------------------------------------------------------------
__global__ __launch_bounds__(256) void zero_part(float* __restrict__ p,
                                                 unsigned* __restrict__ bar)
{
  const size_t i = (size_t)blockIdx.x * 256 + threadIdx.x;
  ((float4*)p)[i] = (float4){0.f, 0.f, 0.f, 0.f};
  if (blockIdx.x == 0 && threadIdx.x < 64) bar[threadIdx.x] = 0u;
}

// ---------------------------------------------------------------------------
// Projection GEMM v3 (unchanged, ~80-110 us): zero-duplication tiling.
// ---------------------------------------------------------------------------
__global__ __launch_bounds__(512) void proj_gemm(
    const float* __restrict__ x, const float* __restrict__ w,
    float* __restrict__ partial)
{
  const int bid = blockIdx.x;          // 0..255
  const int mb = (bid >> 3) & 3;       // 0..3  (M-tile of 128 rows)
  const int kb = (bid & 7) + (bid >> 5) * 8;   // 0..63 (XCD-clustered)
  const int nchunk = 18 + (kb < 24 ? 1 : 0);
  const int c0 = kb * 18 + (kb < 24 ? kb : 24);

  __shared__ char sm[256 * 256];       // 256 rows (x:0-127, w:128-255) x 256 B

  const int tid = threadIdx.x;
  const int lane = tid & 63;
  const int wv = tid >> 6;             // 0..7
  const int wm2 = wv >> 2;             // 0..1  M-half (64 rows)
  const int wn4 = wv & 3;              // 0..3  N-quarter (32 cols)
  const int fr = lane & 15;
  const int kq = lane >> 4;            // 0..3
  const int l31 = lane & 31;
  const int rpar = lane >> 5;          // 0/1

  const float* gptr = (wv < 4)
      ? (x + (size_t)(mb * 128 + wv * 32 + rpar) * KIN + l31 * 4)
      : (w + (size_t)((wv - 4) * 32 + rpar) * KIN + l31 * 4);

  f32x4 acc[4][2];
  #pragma unroll
  for (int mi = 0; mi < 4; ++mi) {
    acc[mi][0] = (f32x4){0.f, 0.f, 0.f, 0.f};
    acc[mi][1] = (f32x4){0.f, 0.f, 0.f, 0.f};
  }

  float4 rv[16];
  {
    const float* base = gptr + (size_t)c0 * 128;
    #pragma unroll
    for (int j = 0; j < 16; ++j)
      rv[j] = *(const float4*)(base + (size_t)(j * 2) * KIN);
  }

  for (int cc = 0; cc < nchunk; ++cc) {
    #pragma unroll
    for (int j = 0; j < 16; ++j) {
      const int r = wv * 32 + j * 2 + rpar;
      const int phys = (l31 * 8) ^ ((r & 7) << 4);
      ushort4 bq = {f2bf(rv[j].x), f2bf(rv[j].y), f2bf(rv[j].z), f2bf(rv[j].w)};
      *(ushort4*)(sm + r * 256 + phys) = bq;
    }
    __syncthreads();
    if (cc + 1 < nchunk) {
      const float* base = gptr + (size_t)(c0 + cc + 1) * 128;
      #pragma unroll
      for (int j = 0; j < 16; ++j)
        rv[j] = *(const float4*)(base + (size_t)(j * 2) * KIN);
    }
    #pragma unroll
    for (int ks = 0; ks < 4; ++ks) {
      const int log = ks * 64 + kq * 16;
      bf16x8 a[4];
      #pragma unroll
      for (int mi = 0; mi < 4; ++mi) {
        const int row = wm2 * 64 + mi * 16 + fr;
        a[mi] = *(const bf16x8*)(sm + row * 256 + (log ^ ((row & 7) << 4)));
      }
      #pragma unroll
      for (int ni = 0; ni < 2; ++ni) {
        const int row = 128 + wn4 * 32 + ni * 16 + fr;
        const bf16x8 b = *(const bf16x8*)(sm + row * 256 + (log ^ ((row & 7) << 4)));
        #pragma unroll
        for (int mi = 0; mi < 4; ++mi)
          acc[mi][ni] = __builtin_amdgcn_mfma_f32_16x16x32_bf16(a[mi], b, acc[mi][ni], 0, 0, 0);
      }
    }
    __syncthreads();
  }
  float* hp = partial + (size_t)(kb & 15) * (MTOK * HIDDEN);
  #pragma unroll
  for (int mi = 0; mi < 4; ++mi)
    #pragma unroll
    for (int ni = 0; ni < 2; ++ni)
      #pragma unroll
      for (int r = 0; r < 4; ++r) {
        const int row = mb * 128 + wm2 * 64 + mi * 16 + kq * 4 + r;
        const int col = wn4 * 32 + ni * 16 + fr;
        atomicAdd(hp + (size_t)row * HIDDEN + col, acc[mi][ni][r]);
      }
}

// ---------------------------------------------------------------------------
// tail_pers: entire post-GEMM pipeline, ONE normal kernel, hand-rolled
// one-shot grid barriers (12). Phase code identical to R4 (proven correct).
// ---------------------------------------------------------------------------
struct TailArgs {
  const float* part; const float* pb;
  float* h; float* hs; float* gate;
  float* uT; float* dtT; float* Bm; float* Cm; float* y;
  float* out;
  const float* ipw; const float* cw; const float* cb;
  const float* xpw; const float* dtw; const float* dtb;
  const float* Alog; const float* Dssm; const float* opw;
  const float* nw; const float* nwf;
  unsigned* bar;
};

__global__ __launch_bounds__(512) void tail_pers(TailArgs A)
{
  const int blk = blockIdx.x;
  const int tid = threadIdx.x;
  const int m0 = blk * 2;
  int bk = 0;                               // running barrier slot index

  __shared__ __align__(16) char smraw[15360];

  // ---------------- phase A0: h = pb + sum(part) ; rms ; in_proj l=0 -------
  {
    float* hrow = (float*)smraw;             // [2][128]
    float* hn   = hrow + 256;                // [2][128]
    const int o2 = tid >> 1, half = tid & 1;
    const int t = o2 >> 7, d = o2 & 127;
    if (half == 0) {
      float hv = A.pb[d];
      #pragma unroll
      for (int s = 0; s < 16; ++s)
        hv += A.part[(size_t)s * (MTOK * HIDDEN) + (size_t)(m0 + t) * 128 + d];
      A.h[(size_t)(m0 + t) * 128 + d] = hv;
      hrow[t * 128 + d] = hv;
    }
    __syncthreads();
    {
      const int wvi = tid >> 6, ln = tid & 63;
      const int tt = wvi & 1;
      const float v0 = hrow[tt * 128 + ln], v1 = hrow[tt * 128 + ln + 64];
      float ss = v0 * v0 + v1 * v1;
      #pragma unroll
      for (int off = 1; off < 64; off <<= 1) ss += __shfl_xor(ss, off);
      const float rr = rsqrtf(ss * (1.0f / 128.0f) + EPS_RMS);
      if (wvi < 2) {
        hn[tt * 128 + ln]      = v0 * rr * A.nw[ln];
        hn[tt * 128 + ln + 64] = v1 * rr * A.nw[ln + 64];
      }
    }
    __syncthreads();
    #pragma unroll
    for (int j = 0; j < 4; ++j) {
      const int o = tid + j * 512;
      const int tt = o >> 10, e = o & 1023;
      const float4* hp4 = (const float4*)(hn + tt * 128);
      const float4* wp4 = (const float4*)(A.ipw + (size_t)e * 128);
      float a0 = 0.f, a1 = 0.f, a2 = 0.f, a3 = 0.f;
      #pragma unroll
      for (int kk = 0; kk < 32; ++kk) {
        const float4 hvv = hp4[kk], wv4 = wp4[kk];
        a0 += hvv.x * wv4.x; a1 += hvv.y * wv4.y;
        a2 += hvv.z * wv4.z; a3 += hvv.w * wv4.w;
      }
      const float a = (a0 + a1) + (a2 + a3);
      if (e < 512) A.hs[(size_t)(m0 + tt) * 512 + e] = a;
      else         A.gate[(size_t)(m0 + tt) * 512 + (e - 512)] = a;
    }
  }
  gbar(A.bar + bk++);

  for (int l = 0; l < DEPTH; ++l) {
    // -------------- phase CONV(l): conv+silu -> uT ; x_proj ; dt ----------
    {
      float* hs5 = (float*)smraw;            // [5][512]
      float* u4  = hs5 + 2560;               // [2][512]
      float* si  = u4 + 1024;                // [2][40]
      const float* cw  = A.cw  + (size_t)l * 2048;
      const float* cb  = A.cb  + (size_t)l * 512;
      const float* xpw = A.xpw + (size_t)l * 40 * 512;
      const float* dtw = A.dtw + (size_t)l * 512 * 8;
      const float* dtb = A.dtb + (size_t)l * 512;
      const int b = m0 >> 8, tb0 = m0 & 255;
      for (int o = tid; o < 2560; o += 512) {
        const int j = o >> 9, i = o & 511;
        const int ct = tb0 - 3 + j;
        hs5[j * 512 + i] = (ct >= 0) ? A.hs[((size_t)b * 256 + ct) * 512 + i] : 0.f;
      }
      __syncthreads();
      #pragma unroll
      for (int j = 0; j < 2; ++j) {
        const int o = tid + j * 512;
        const int t = o >> 9, i = o & 511;
        const float4 c4v = *(const float4*)(cw + (size_t)i * 4);
        const float s = cb[i] + c4v.x * hs5[t * 512 + i] + c4v.y * hs5[(t + 1) * 512 + i]
                              + c4v.z * hs5[(t + 2) * 512 + i] + c4v.w * hs5[(t + 3) * 512 + i];
        const float uu = silu_f(s);
        u4[t * 512 + i] = uu;
        A.uT[((size_t)b * 512 + i) * 256 + tb0 + t] = uu;
      }
      __syncthreads();
      if (tid < 160) {
        const int pid = tid >> 1, half = tid & 1;
        const int t = pid / 40, e = pid % 40;
        const float4* up = (const float4*)(u4 + t * 512 + half * 256);
        const float4* wp = (const float4*)(xpw + (size_t)e * 512 + half * 256);
        float a0 = 0.f, a1 = 0.f, a2 = 0.f, a3 = 0.f;
        #pragma unroll 8
        for (int kk = 0; kk < 64; ++kk) {
          const float4 uv = up[kk], wv4 = wp[kk];
          a0 += uv.x * wv4.x; a1 += uv.y * wv4.y;
          a2 += uv.z * wv4.z; a3 += uv.w * wv4.w;
        }
        float a = (a0 + a1) + (a2 + a3);
        a += __shfl_xor(a, 1);
        if (half == 0) si[t * 40 + e] = a;
      }
      __syncthreads();
      if (tid < 64) {
        const int t = tid >> 5, q = tid & 31;
        if (q < 16) A.Bm[(size_t)(m0 + t) * 16 + q] = si[t * 40 + 8 + q];
        else        A.Cm[(size_t)(m0 + t) * 16 + (q - 16)] = si[t * 40 + 24 + (q - 16)];
      }
      #pragma unroll
      for (int j = 0; j < 2; ++j) {
        const int o = tid + j * 512;
        const int i = o >> 1, t = o & 1;
        float a0 = dtb[i];
        const float* dr = dtw + (size_t)i * 8;
        #pragma unroll
        for (int r = 0; r < 8; ++r) a0 += si[t * 40 + r] * dr[r];
        const float sp = (a0 > 20.f) ? a0 : log1pf(__expf(a0));
        A.dtT[((size_t)b * 512 + i) * 256 + tb0 + t] = sp;
      }
    }
    gbar(A.bar + bk++);

    // -------------- phase SCAN(l): 4 scans/block (2 parallel x 2 rounds) --
    {
      float* dt_l = (float*)smraw;           // [2][256]
      float* u_l  = dt_l + 512;              // [2][256]
      float* e_l  = u_l + 512;               // [2][16*17]
      float* P_l  = e_l + 544;               // [2][16*17]
      const float* Alg = A.Alog + (size_t)l * INTER * NSTATE;
      const float* Dsp = A.Dssm + (size_t)l * INTER;
      const int sub = tid >> 8;              // 0/1
      const int t2 = tid & 255;
      const int c = t2 >> 4, n = t2 & 15;
      for (int rd = 0; rd < 2; ++rd) {
        const int unit = blk * 4 + sub * 2 + rd;
        const int b = unit >> 9, i = unit & 511;
        dt_l[sub * 256 + t2] = A.dtT[((size_t)b * 512 + i) * 256 + t2];
        u_l [sub * 256 + t2] = A.uT [((size_t)b * 512 + i) * 256 + t2];
        const float Av = -__expf(Alg[(size_t)i * 16 + n]);
        const float Dv = Dsp[i];
        float Bv[16], Cv[16];
        #pragma unroll
        for (int j = 0; j < 16; ++j) {
          const int t = c * 16 + j;
          Bv[j] = A.Bm[(size_t)b * 4096 + t * 16 + n];
          Cv[j] = A.Cm[(size_t)b * 4096 + t * 16 + n];
        }
        __syncthreads();
        float aj[16];
        float s = 0.f, P = 1.f;
        #pragma unroll
        for (int j = 0; j < 16; ++j) {     // pass 1: local scan from 0
          const int t = c * 16 + j;
          const float dtv = dt_l[sub * 256 + t];
          const float a = __expf(Av * dtv);
          aj[j] = a;
          s = a * s + dtv * Bv[j] * u_l[sub * 256 + t];
          P *= a;
        }
        e_l[sub * 272 + c * 17 + n] = s;
        P_l[sub * 272 + c * 17 + n] = P;
        __syncthreads();
        float s0 = 0.f;                    // stitch chunk prefixes
        for (int cc = 0; cc < c; ++cc)
          s0 = P_l[sub * 272 + cc * 17 + n] * s0 + e_l[sub * 272 + cc * 17 + n];
        s = s0;
        #pragma unroll
        for (int j = 0; j < 16; ++j) {     // pass 2: replay with true state
          const int t = c * 16 + j;
          const float dtv = dt_l[sub * 256 + t];
          s = aj[j] * s + dtv * Bv[j] * u_l[sub * 256 + t];
          float p = s * Cv[j];
          p += __shfl_xor(p, 1); p += __shfl_xor(p, 2);
          p += __shfl_xor(p, 4); p += __shfl_xor(p, 8);
          if (n == 0)
            A.y[((size_t)b * 256 + t) * 512 + i] = p + u_l[sub * 256 + t] * Dv;
        }
        __syncthreads();
      }
    }
    gbar(A.bar + bk++);

    // -------------- phase FA(l): out_proj+res ; rms ; in_proj(l+1)|out ----
    {
      float* y2   = (float*)smraw;           // [2][512]
      float* hrow = y2 + 1024;               // [2][128]
      float* hn   = hrow + 256;              // [2][128]
      const float* opw = A.opw + (size_t)l * 128 * 512;
      const int o2 = tid >> 1, half = tid & 1;
      const int t = o2 >> 7, d = o2 & 127;
      #pragma unroll
      for (int j = 0; j < 2; ++j) {
        const int o = tid + j * 512;
        const int tt = o >> 9, i = o & 511;
        const float yv = A.y[(size_t)(m0 + tt) * 512 + i];
        const float g  = A.gate[(size_t)(m0 + tt) * 512 + i];
        y2[tt * 512 + i] = yv * silu_f(g);
      }
      __syncthreads();
      {
        const float4* yp = (const float4*)(y2 + t * 512 + half * 256);
        const float4* wp = (const float4*)(opw + (size_t)d * 512 + half * 256);
        float a0 = 0.f, a1 = 0.f, a2 = 0.f, a3 = 0.f;
        #pragma unroll 8
        for (int kk = 0; kk < 64; ++kk) {
          const float4 yv = yp[kk], wv4 = wp[kk];
          a0 += yv.x * wv4.x; a1 += yv.y * wv4.y;
          a2 += yv.z * wv4.z; a3 += yv.w * wv4.w;
        }
        float a = (a0 + a1) + (a2 + a3);
        a += __shfl_xor(a, 1);
        const float hv = A.h[(size_t)(m0 + t) * 128 + d] + a;
        if (l < 3 && half == 0) A.h[(size_t)(m0 + t) * 128 + d] = hv;
        if (half == 0) hrow[t * 128 + d] = hv;
      }
      __syncthreads();
      const float* nwp = (l < 3) ? (A.nw + (size_t)(l + 1) * 128) : A.nwf;
      {
        const int wvi = tid >> 6, ln = tid & 63;
        const int tt = wvi & 1;
        const float v0 = hrow[tt * 128 + ln], v1 = hrow[tt * 128 + ln + 64];
        float ss = v0 * v0 + v1 * v1;
        #pragma unroll
        for (int off = 1; off < 64; off <<= 1) ss += __shfl_xor(ss, off);
        const float rr = rsqrtf(ss * (1.0f / 128.0f) + EPS_RMS);
        if (l == 3) {
          if (wvi < 2) {
            A.out[(size_t)(m0 + tt) * 128 + ln]      = v0 * rr * nwp[ln];
            A.out[(size_t)(m0 + tt) * 128 + ln + 64] = v1 * rr * nwp[ln + 64];
          }
        } else if (wvi < 2) {
          hn[tt * 128 + ln]      = v0 * rr * nwp[ln];
          hn[tt * 128 + ln + 64] = v1 * rr * nwp[ln + 64];
        }
      }
      if (l < 3) {
        __syncthreads();
        const float* ipw = A.ipw + (size_t)(l + 1) * 1024 * 128;
        #pragma unroll
        for (int j = 0; j < 4; ++j) {
          const int o = tid + j * 512;
          const int tt = o >> 10, e = o & 1023;
          const float4* hp4 = (const float4*)(hn + tt * 128);
          const float4* wp4 = (const float4*)(ipw + (size_t)e * 128);
          float a0 = 0.f, a1 = 0.f, a2 = 0.f, a3 = 0.f;
          #pragma unroll
          for (int kk = 0; kk < 32; ++kk) {
            const float4 hvv = hp4[kk], wv4 = wp4[kk];
            a0 += hvv.x * wv4.x; a1 += hvv.y * wv4.y;
            a2 += hvv.z * wv4.z; a3 += hvv.w * wv4.w;
          }
          const float a = (a0 + a1) + (a2 + a3);
          if (e < 512) A.hs[(size_t)(m0 + tt) * 512 + e] = a;
          else         A.gate[(size_t)(m0 + tt) * 512 + (e - 512)] = a;
        }
      }
    }
    if (l < 3) gbar(A.bar + bk++);
  }
}

extern "C" void kernel_launch(void* const* d_in, const int* in_sizes, int n_in,
                              void* d_out, int out_size, void* d_ws, size_t ws_size,
                              hipStream_t stream)
{
  (void)in_sizes; (void)n_in; (void)out_size; (void)ws_size;
  const float* x    = (const float*)d_in[0];
  const float* pw   = (const float*)d_in[1];
  const float* pb   = (const float*)d_in[2];
  const float* ipw  = (const float*)d_in[3];
  const float* cw   = (const float*)d_in[4];
  const float* cb   = (const float*)d_in[5];
  const float* xpw  = (const float*)d_in[6];
  const float* dtw  = (const float*)d_in[7];
  const float* dtb  = (const float*)d_in[8];
  const float* Alog = (const float*)d_in[9];
  const float* Dssm = (const float*)d_in[10];
  const float* opw  = (const float*)d_in[11];
  const float* nw   = (const float*)d_in[12];
  const float* nwf  = (const float*)d_in[13];
  float* out = (float*)d_out;

  float* ws   = (float*)d_ws;                 // ~10 MB scratch
  float* part = ws;                           // 16 * 65536 (atomic-accumulated)
  float* h    = part + 16 * 65536;            // 65536
  float* hs   = h + 65536;                    // 262144
  float* gate = hs + 262144;                  // 262144
  float* uT   = gate + 262144;                // 262144
  float* dtT  = uT + 262144;                  // 262144
  float* Bm   = dtT + 262144;                 // 8192
  float* Cm   = Bm + 8192;                    // 8192
  float* y    = Cm + 8192;                    // 262144
  unsigned* bar = (unsigned*)(y + 262144);    // 64 slots

  zero_part<<<dim3(1024), 256, 0, stream>>>(part, bar);
  proj_gemm<<<dim3(256), 512, 0, stream>>>(x, pw, part);

  TailArgs ta;
  ta.part = part; ta.pb = pb;
  ta.h = h; ta.hs = hs; ta.gate = gate;
  ta.uT = uT; ta.dtT = dtT; ta.Bm = Bm; ta.Cm = Cm; ta.y = y;
  ta.out = out;
  ta.ipw = ipw; ta.cw = cw; ta.cb = cb;
  ta.xpw = xpw; ta.dtw = dtw; ta.dtb = dtb;
  ta.Alog = Alog; ta.Dssm = Dssm; ta.opw = opw;
  ta.nw = nw; ta.nwf = nwf;
  ta.bar = bar;

  tail_pers<<<dim3(NBLK), 512, 0, stream>>>(ta);
}

// Round 6
// 533.969 us; speedup vs baseline: 1.3591x; 1.2127x over previous
//
#include <hip/hip_runtime.h>
#include <hip/hip_bf16.h>

#define HIDDEN 128
#define DEPTH 4
#define INTER 512
#define NSTATE 16
#define DT_RANK 8
#define EPS_RMS 1e-5f
#define MTOK 512            // B*T
#define KIN 150528
#define NBLK 256            // tail persistent-kernel grid

typedef __attribute__((ext_vector_type(8))) short bf16x8;
typedef __attribute__((ext_vector_type(4))) float f32x4;

__device__ __forceinline__ unsigned short f2bf(float f) {
  unsigned int u = __builtin_bit_cast(unsigned int, f);
  u += 0x7fffu + ((u >> 16) & 1u);
  return (unsigned short)(u >> 16);
}
__device__ __forceinline__ float silu_f(float x) {
  return x / (1.0f + __expf(-x));
}

// ---------------------------------------------------------------------------
// One-shot grid barrier, v2. R5's version spun with ACQUIRE@agent polls:
// every poll emitted L1/L2 cache-maintenance (per-XCD L2 non-coherent), so
// 256 spinners thrashed the L2s ~every 0.2us -> 40us/barrier AND slowed the
// working blocks' weight reads. Fix: ordering ops exactly ONCE per block:
//   arrive = fetch_add(RELEASE)        (one L2 writeback, carries release)
//   spin   = RELAXED polls + s_sleep   (atomics act at coherence point; no
//                                       cache ops per poll)
//   exit   = one ACQUIRE load          (single invalidate per block)
// ---------------------------------------------------------------------------
__device__ __forceinline__ void gbar(unsigned* slot)
{
  __syncthreads();
  if (threadIdx.x == 0) {
    (void)__hip_atomic_fetch_add(slot, 1u, __ATOMIC_RELEASE,
                                 __HIP_MEMORY_SCOPE_AGENT);
    while (__hip_atomic_load(slot, __ATOMIC_RELAXED,
                             __HIP_MEMORY_SCOPE_AGENT) < (unsigned)NBLK)
      __builtin_amdgcn_s_sleep(16);
    (void)__hip_atomic_load(slot, __ATOMIC_ACQUIRE,
                            __HIP_MEMORY_SCOPE_AGENT);   // one inv, then go
  }
  __syncthreads();
}

// ---------------------------------------------------------------------------
// zero_part: 4 MB partial buffer zero + barrier-slot zero.
// ---------------------------------------------------------------------------
__global__ __launch_bounds__(256) void zero_part(float* __restrict__ p,
                                                 unsigned* __restrict__ bar)
{
  const size_t i = (size_t)blockIdx.x * 256 + threadIdx.x;
  ((float4*)p)[i] = (float4){0.f, 0.f, 0.f, 0.f};
  if (blockIdx.x == 0 && threadIdx.x < 64) bar[threadIdx.x] = 0u;
}

// ---------------------------------------------------------------------------
// Projection GEMM v3 (unchanged, ~80-110 us): zero-duplication tiling.
// ---------------------------------------------------------------------------
__global__ __launch_bounds__(512) void proj_gemm(
    const float* __restrict__ x, const float* __restrict__ w,
    float* __restrict__ partial)
{
  const int bid = blockIdx.x;          // 0..255
  const int mb = (bid >> 3) & 3;       // 0..3  (M-tile of 128 rows)
  const int kb = (bid & 7) + (bid >> 5) * 8;   // 0..63 (XCD-clustered)
  const int nchunk = 18 + (kb < 24 ? 1 : 0);
  const int c0 = kb * 18 + (kb < 24 ? kb : 24);

  __shared__ char sm[256 * 256];       // 256 rows (x:0-127, w:128-255) x 256 B

  const int tid = threadIdx.x;
  const int lane = tid & 63;
  const int wv = tid >> 6;             // 0..7
  const int wm2 = wv >> 2;             // 0..1  M-half (64 rows)
  const int wn4 = wv & 3;              // 0..3  N-quarter (32 cols)
  const int fr = lane & 15;
  const int kq = lane >> 4;            // 0..3
  const int l31 = lane & 31;
  const int rpar = lane >> 5;          // 0/1

  const float* gptr = (wv < 4)
      ? (x + (size_t)(mb * 128 + wv * 32 + rpar) * KIN + l31 * 4)
      : (w + (size_t)((wv - 4) * 32 + rpar) * KIN + l31 * 4);

  f32x4 acc[4][2];
  #pragma unroll
  for (int mi = 0; mi < 4; ++mi) {
    acc[mi][0] = (f32x4){0.f, 0.f, 0.f, 0.f};
    acc[mi][1] = (f32x4){0.f, 0.f, 0.f, 0.f};
  }

  float4 rv[16];
  {
    const float* base = gptr + (size_t)c0 * 128;
    #pragma unroll
    for (int j = 0; j < 16; ++j)
      rv[j] = *(const float4*)(base + (size_t)(j * 2) * KIN);
  }

  for (int cc = 0; cc < nchunk; ++cc) {
    #pragma unroll
    for (int j = 0; j < 16; ++j) {
      const int r = wv * 32 + j * 2 + rpar;
      const int phys = (l31 * 8) ^ ((r & 7) << 4);
      ushort4 bq = {f2bf(rv[j].x), f2bf(rv[j].y), f2bf(rv[j].z), f2bf(rv[j].w)};
      *(ushort4*)(sm + r * 256 + phys) = bq;
    }
    __syncthreads();
    if (cc + 1 < nchunk) {
      const float* base = gptr + (size_t)(c0 + cc + 1) * 128;
      #pragma unroll
      for (int j = 0; j < 16; ++j)
        rv[j] = *(const float4*)(base + (size_t)(j * 2) * KIN);
    }
    #pragma unroll
    for (int ks = 0; ks < 4; ++ks) {
      const int log = ks * 64 + kq * 16;
      bf16x8 a[4];
      #pragma unroll
      for (int mi = 0; mi < 4; ++mi) {
        const int row = wm2 * 64 + mi * 16 + fr;
        a[mi] = *(const bf16x8*)(sm + row * 256 + (log ^ ((row & 7) << 4)));
      }
      #pragma unroll
      for (int ni = 0; ni < 2; ++ni) {
        const int row = 128 + wn4 * 32 + ni * 16 + fr;
        const bf16x8 b = *(const bf16x8*)(sm + row * 256 + (log ^ ((row & 7) << 4)));
        #pragma unroll
        for (int mi = 0; mi < 4; ++mi)
          acc[mi][ni] = __builtin_amdgcn_mfma_f32_16x16x32_bf16(a[mi], b, acc[mi][ni], 0, 0, 0);
      }
    }
    __syncthreads();
  }
  float* hp = partial + (size_t)(kb & 15) * (MTOK * HIDDEN);
  #pragma unroll
  for (int mi = 0; mi < 4; ++mi)
    #pragma unroll
    for (int ni = 0; ni < 2; ++ni)
      #pragma unroll
      for (int r = 0; r < 4; ++r) {
        const int row = mb * 128 + wm2 * 64 + mi * 16 + kq * 4 + r;
        const int col = wn4 * 32 + ni * 16 + fr;
        atomicAdd(hp + (size_t)row * HIDDEN + col, acc[mi][ni][r]);
      }
}

// ---------------------------------------------------------------------------
// tail_pers: entire post-GEMM pipeline, ONE normal kernel, hand-rolled
// one-shot grid barriers (12). Phase code identical to R4/R5 (proven).
// ---------------------------------------------------------------------------
struct TailArgs {
  const float* part; const float* pb;
  float* h; float* hs; float* gate;
  float* uT; float* dtT; float* Bm; float* Cm; float* y;
  float* out;
  const float* ipw; const float* cw; const float* cb;
  const float* xpw; const float* dtw; const float* dtb;
  const float* Alog; const float* Dssm; const float* opw;
  const float* nw; const float* nwf;
  unsigned* bar;
};

__global__ __launch_bounds__(512) void tail_pers(TailArgs A)
{
  const int blk = blockIdx.x;
  const int tid = threadIdx.x;
  const int m0 = blk * 2;
  int bk = 0;                               // running barrier slot index

  __shared__ __align__(16) char smraw[15360];

  // ---------------- phase A0: h = pb + sum(part) ; rms ; in_proj l=0 -------
  {
    float* hrow = (float*)smraw;             // [2][128]
    float* hn   = hrow + 256;                // [2][128]
    const int o2 = tid >> 1, half = tid & 1;
    const int t = o2 >> 7, d = o2 & 127;
    if (half == 0) {
      float hv = A.pb[d];
      #pragma unroll
      for (int s = 0; s < 16; ++s)
        hv += A.part[(size_t)s * (MTOK * HIDDEN) + (size_t)(m0 + t) * 128 + d];
      A.h[(size_t)(m0 + t) * 128 + d] = hv;
      hrow[t * 128 + d] = hv;
    }
    __syncthreads();
    {
      const int wvi = tid >> 6, ln = tid & 63;
      const int tt = wvi & 1;
      const float v0 = hrow[tt * 128 + ln], v1 = hrow[tt * 128 + ln + 64];
      float ss = v0 * v0 + v1 * v1;
      #pragma unroll
      for (int off = 1; off < 64; off <<= 1) ss += __shfl_xor(ss, off);
      const float rr = rsqrtf(ss * (1.0f / 128.0f) + EPS_RMS);
      if (wvi < 2) {
        hn[tt * 128 + ln]      = v0 * rr * A.nw[ln];
        hn[tt * 128 + ln + 64] = v1 * rr * A.nw[ln + 64];
      }
    }
    __syncthreads();
    #pragma unroll
    for (int j = 0; j < 4; ++j) {
      const int o = tid + j * 512;
      const int tt = o >> 10, e = o & 1023;
      const float4* hp4 = (const float4*)(hn + tt * 128);
      const float4* wp4 = (const float4*)(A.ipw + (size_t)e * 128);
      float a0 = 0.f, a1 = 0.f, a2 = 0.f, a3 = 0.f;
      #pragma unroll
      for (int kk = 0; kk < 32; ++kk) {
        const float4 hvv = hp4[kk], wv4 = wp4[kk];
        a0 += hvv.x * wv4.x; a1 += hvv.y * wv4.y;
        a2 += hvv.z * wv4.z; a3 += hvv.w * wv4.w;
      }
      const float a = (a0 + a1) + (a2 + a3);
      if (e < 512) A.hs[(size_t)(m0 + tt) * 512 + e] = a;
      else         A.gate[(size_t)(m0 + tt) * 512 + (e - 512)] = a;
    }
  }
  gbar(A.bar + bk++);

  for (int l = 0; l < DEPTH; ++l) {
    // -------------- phase CONV(l): conv+silu -> uT ; x_proj ; dt ----------
    {
      float* hs5 = (float*)smraw;            // [5][512]
      float* u4  = hs5 + 2560;               // [2][512]
      float* si  = u4 + 1024;                // [2][40]
      const float* cw  = A.cw  + (size_t)l * 2048;
      const float* cb  = A.cb  + (size_t)l * 512;
      const float* xpw = A.xpw + (size_t)l * 40 * 512;
      const float* dtw = A.dtw + (size_t)l * 512 * 8;
      const float* dtb = A.dtb + (size_t)l * 512;
      const int b = m0 >> 8, tb0 = m0 & 255;
      for (int o = tid; o < 2560; o += 512) {
        const int j = o >> 9, i = o & 511;
        const int ct = tb0 - 3 + j;
        hs5[j * 512 + i] = (ct >= 0) ? A.hs[((size_t)b * 256 + ct) * 512 + i] : 0.f;
      }
      __syncthreads();
      #pragma unroll
      for (int j = 0; j < 2; ++j) {
        const int o = tid + j * 512;
        const int t = o >> 9, i = o & 511;
        const float4 c4v = *(const float4*)(cw + (size_t)i * 4);
        const float s = cb[i] + c4v.x * hs5[t * 512 + i] + c4v.y * hs5[(t + 1) * 512 + i]
                              + c4v.z * hs5[(t + 2) * 512 + i] + c4v.w * hs5[(t + 3) * 512 + i];
        const float uu = silu_f(s);
        u4[t * 512 + i] = uu;
        A.uT[((size_t)b * 512 + i) * 256 + tb0 + t] = uu;
      }
      __syncthreads();
      if (tid < 160) {
        const int pid = tid >> 1, half = tid & 1;
        const int t = pid / 40, e = pid % 40;
        const float4* up = (const float4*)(u4 + t * 512 + half * 256);
        const float4* wp = (const float4*)(xpw + (size_t)e * 512 + half * 256);
        float a0 = 0.f, a1 = 0.f, a2 = 0.f, a3 = 0.f;
        #pragma unroll 8
        for (int kk = 0; kk < 64; ++kk) {
          const float4 uv = up[kk], wv4 = wp[kk];
          a0 += uv.x * wv4.x; a1 += uv.y * wv4.y;
          a2 += uv.z * wv4.z; a3 += uv.w * wv4.w;
        }
        float a = (a0 + a1) + (a2 + a3);
        a += __shfl_xor(a, 1);
        if (half == 0) si[t * 40 + e] = a;
      }
      __syncthreads();
      if (tid < 64) {
        const int t = tid >> 5, q = tid & 31;
        if (q < 16) A.Bm[(size_t)(m0 + t) * 16 + q] = si[t * 40 + 8 + q];
        else        A.Cm[(size_t)(m0 + t) * 16 + (q - 16)] = si[t * 40 + 24 + (q - 16)];
      }
      #pragma unroll
      for (int j = 0; j < 2; ++j) {
        const int o = tid + j * 512;
        const int i = o >> 1, t = o & 1;
        float a0 = dtb[i];
        const float* dr = dtw + (size_t)i * 8;
        #pragma unroll
        for (int r = 0; r < 8; ++r) a0 += si[t * 40 + r] * dr[r];
        const float sp = (a0 > 20.f) ? a0 : log1pf(__expf(a0));
        A.dtT[((size_t)b * 512 + i) * 256 + tb0 + t] = sp;
      }
    }
    gbar(A.bar + bk++);

    // -------------- phase SCAN(l): 4 scans/block (2 parallel x 2 rounds) --
    {
      float* dt_l = (float*)smraw;           // [2][256]
      float* u_l  = dt_l + 512;              // [2][256]
      float* e_l  = u_l + 512;               // [2][16*17]
      float* P_l  = e_l + 544;               // [2][16*17]
      const float* Alg = A.Alog + (size_t)l * INTER * NSTATE;
      const float* Dsp = A.Dssm + (size_t)l * INTER;
      const int sub = tid >> 8;              // 0/1
      const int t2 = tid & 255;
      const int c = t2 >> 4, n = t2 & 15;
      for (int rd = 0; rd < 2; ++rd) {
        const int unit = blk * 4 + sub * 2 + rd;
        const int b = unit >> 9, i = unit & 511;
        dt_l[sub * 256 + t2] = A.dtT[((size_t)b * 512 + i) * 256 + t2];
        u_l [sub * 256 + t2] = A.uT [((size_t)b * 512 + i) * 256 + t2];
        const float Av = -__expf(Alg[(size_t)i * 16 + n]);
        const float Dv = Dsp[i];
        float Bv[16], Cv[16];
        #pragma unroll
        for (int j = 0; j < 16; ++j) {
          const int t = c * 16 + j;
          Bv[j] = A.Bm[(size_t)b * 4096 + t * 16 + n];
          Cv[j] = A.Cm[(size_t)b * 4096 + t * 16 + n];
        }
        __syncthreads();
        float aj[16];
        float s = 0.f, P = 1.f;
        #pragma unroll
        for (int j = 0; j < 16; ++j) {     // pass 1: local scan from 0
          const int t = c * 16 + j;
          const float dtv = dt_l[sub * 256 + t];
          const float a = __expf(Av * dtv);
          aj[j] = a;
          s = a * s + dtv * Bv[j] * u_l[sub * 256 + t];
          P *= a;
        }
        e_l[sub * 272 + c * 17 + n] = s;
        P_l[sub * 272 + c * 17 + n] = P;
        __syncthreads();
        float s0 = 0.f;                    // stitch chunk prefixes
        for (int cc = 0; cc < c; ++cc)
          s0 = P_l[sub * 272 + cc * 17 + n] * s0 + e_l[sub * 272 + cc * 17 + n];
        s = s0;
        #pragma unroll
        for (int j = 0; j < 16; ++j) {     // pass 2: replay with true state
          const int t = c * 16 + j;
          const float dtv = dt_l[sub * 256 + t];
          s = aj[j] * s + dtv * Bv[j] * u_l[sub * 256 + t];
          float p = s * Cv[j];
          p += __shfl_xor(p, 1); p += __shfl_xor(p, 2);
          p += __shfl_xor(p, 4); p += __shfl_xor(p, 8);
          if (n == 0)
            A.y[((size_t)b * 256 + t) * 512 + i] = p + u_l[sub * 256 + t] * Dv;
        }
        __syncthreads();
      }
    }
    gbar(A.bar + bk++);

    // -------------- phase FA(l): out_proj+res ; rms ; in_proj(l+1)|out ----
    {
      float* y2   = (float*)smraw;           // [2][512]
      float* hrow = y2 + 1024;               // [2][128]
      float* hn   = hrow + 256;              // [2][128]
      const float* opw = A.opw + (size_t)l * 128 * 512;
      const int o2 = tid >> 1, half = tid & 1;
      const int t = o2 >> 7, d = o2 & 127;
      #pragma unroll
      for (int j = 0; j < 2; ++j) {
        const int o = tid + j * 512;
        const int tt = o >> 9, i = o & 511;
        const float yv = A.y[(size_t)(m0 + tt) * 512 + i];
        const float g  = A.gate[(size_t)(m0 + tt) * 512 + i];
        y2[tt * 512 + i] = yv * silu_f(g);
      }
      __syncthreads();
      {
        const float4* yp = (const float4*)(y2 + t * 512 + half * 256);
        const float4* wp = (const float4*)(opw + (size_t)d * 512 + half * 256);
        float a0 = 0.f, a1 = 0.f, a2 = 0.f, a3 = 0.f;
        #pragma unroll 8
        for (int kk = 0; kk < 64; ++kk) {
          const float4 yv = yp[kk], wv4 = wp[kk];
          a0 += yv.x * wv4.x; a1 += yv.y * wv4.y;
          a2 += yv.z * wv4.z; a3 += yv.w * wv4.w;
        }
        float a = (a0 + a1) + (a2 + a3);
        a += __shfl_xor(a, 1);
        const float hv = A.h[(size_t)(m0 + t) * 128 + d] + a;
        if (l < 3 && half == 0) A.h[(size_t)(m0 + t) * 128 + d] = hv;
        if (half == 0) hrow[t * 128 + d] = hv;
      }
      __syncthreads();
      const float* nwp = (l < 3) ? (A.nw + (size_t)(l + 1) * 128) : A.nwf;
      {
        const int wvi = tid >> 6, ln = tid & 63;
        const int tt = wvi & 1;
        const float v0 = hrow[tt * 128 + ln], v1 = hrow[tt * 128 + ln + 64];
        float ss = v0 * v0 + v1 * v1;
        #pragma unroll
        for (int off = 1; off < 64; off <<= 1) ss += __shfl_xor(ss, off);
        const float rr = rsqrtf(ss * (1.0f / 128.0f) + EPS_RMS);
        if (l == 3) {
          if (wvi < 2) {
            A.out[(size_t)(m0 + tt) * 128 + ln]      = v0 * rr * nwp[ln];
            A.out[(size_t)(m0 + tt) * 128 + ln + 64] = v1 * rr * nwp[ln + 64];
          }
        } else if (wvi < 2) {
          hn[tt * 128 + ln]      = v0 * rr * nwp[ln];
          hn[tt * 128 + ln + 64] = v1 * rr * nwp[ln + 64];
        }
      }
      if (l < 3) {
        __syncthreads();
        const float* ipw = A.ipw + (size_t)(l + 1) * 1024 * 128;
        #pragma unroll
        for (int j = 0; j < 4; ++j) {
          const int o = tid + j * 512;
          const int tt = o >> 10, e = o & 1023;
          const float4* hp4 = (const float4*)(hn + tt * 128);
          const float4* wp4 = (const float4*)(ipw + (size_t)e * 128);
          float a0 = 0.f, a1 = 0.f, a2 = 0.f, a3 = 0.f;
          #pragma unroll
          for (int kk = 0; kk < 32; ++kk) {
            const float4 hvv = hp4[kk], wv4 = wp4[kk];
            a0 += hvv.x * wv4.x; a1 += hvv.y * wv4.y;
            a2 += hvv.z * wv4.z; a3 += hvv.w * wv4.w;
          }
          const float a = (a0 + a1) + (a2 + a3);
          if (e < 512) A.hs[(size_t)(m0 + tt) * 512 + e] = a;
          else         A.gate[(size_t)(m0 + tt) * 512 + (e - 512)] = a;
        }
      }
    }
    if (l < 3) gbar(A.bar + bk++);
  }
}

extern "C" void kernel_launch(void* const* d_in, const int* in_sizes, int n_in,
                              void* d_out, int out_size, void* d_ws, size_t ws_size,
                              hipStream_t stream)
{
  (void)in_sizes; (void)n_in; (void)out_size; (void)ws_size;
  const float* x    = (const float*)d_in[0];
  const float* pw   = (const float*)d_in[1];
  const float* pb   = (const float*)d_in[2];
  const float* ipw  = (const float*)d_in[3];
  const float* cw   = (const float*)d_in[4];
  const float* cb   = (const float*)d_in[5];
  const float* xpw  = (const float*)d_in[6];
  const float* dtw  = (const float*)d_in[7];
  const float* dtb  = (const float*)d_in[8];
  const float* Alog = (const float*)d_in[9];
  const float* Dssm = (const float*)d_in[10];
  const float* opw  = (const float*)d_in[11];
  const float* nw   = (const float*)d_in[12];
  const float* nwf  = (const float*)d_in[13];
  float* out = (float*)d_out;

  float* ws   = (float*)d_ws;                 // ~10 MB scratch
  float* part = ws;                           // 16 * 65536 (atomic-accumulated)
  float* h    = part + 16 * 65536;            // 65536
  float* hs   = h + 65536;                    // 262144
  float* gate = hs + 262144;                  // 262144
  float* uT   = gate + 262144;                // 262144
  float* dtT  = uT + 262144;                  // 262144
  float* Bm   = dtT + 262144;                 // 8192
  float* Cm   = Bm + 8192;                    // 8192
  float* y    = Cm + 8192;                    // 262144
  unsigned* bar = (unsigned*)(y + 262144);    // 64 slots

  zero_part<<<dim3(1024), 256, 0, stream>>>(part, bar);
  proj_gemm<<<dim3(256), 512, 0, stream>>>(x, pw, part);

  TailArgs ta;
  ta.part = part; ta.pb = pb;
  ta.h = h; ta.hs = hs; ta.gate = gate;
  ta.uT = uT; ta.dtT = dtT; ta.Bm = Bm; ta.Cm = Cm; ta.y = y;
  ta.out = out;
  ta.ipw = ipw; ta.cw = cw; ta.cb = cb;
  ta.xpw = xpw; ta.dtw = dtw; ta.dtb = dtb;
  ta.Alog = Alog; ta.Dssm = Dssm; ta.opw = opw;
  ta.nw = nw; ta.nwf = nwf;
  ta.bar = bar;

  tail_pers<<<dim3(NBLK), 512, 0, stream>>>(ta);
}